// Round 6
// baseline (5426.827 us; speedup 1.0000x reference)
//
#include <hip/hip_runtime.h>

// ---------------- problem constants ----------------
#define NUSER 200000
#define NPROD 100000
#define NCAT    2000
#define NQRY   50000
#define EBUYS  500000
#define ESEARCH 300000
#define EMATCH  300000
#define EIN     100000

// type ids: 0=user 1=product 2=category 3=query
// relations t=0..7 (weight-stack index):
//  t0 user->product, t1 product->user, t2 user->query, t3 query->user,
//  t4 query->product, t5 product->query, t6 product->category, t7 category->product
// per-dst relation slots (must match wt_build's relsD):
//  user: {t1,t3}  product: {t0,t4,t7}  category: {t6}  query: {t2,t5}

// ---------------- CSR build ----------------
__global__ __launch_bounds__(256) void count_kernel(const int* __restrict__ dst, int E,
                                                    int* __restrict__ cnt) {
    int i = blockIdx.x * 256 + threadIdx.x;
    if (i < E) atomicAdd(&cnt[dst[i]], 1);
}

__global__ __launch_bounds__(256) void scan_partial(const int* __restrict__ cnt, int n,
                                                    int* __restrict__ bsums) {
    __shared__ int sd[256];
    int base = blockIdx.x * 4096;
    int s = 0;
    for (int j = threadIdx.x; j < 4096; j += 256) {
        int idx = base + j;
        s += (idx < n) ? cnt[idx] : 0;
    }
    sd[threadIdx.x] = s;
    __syncthreads();
    for (int st = 128; st > 0; st >>= 1) {
        if (threadIdx.x < st) sd[threadIdx.x] += sd[threadIdx.x + st];
        __syncthreads();
    }
    if (threadIdx.x == 0) bsums[blockIdx.x] = sd[0];
}

__global__ __launch_bounds__(64) void scan_bsums(int* __restrict__ bs, int nb) {
    int lane = threadIdx.x;
    int orig = (lane < nb) ? bs[lane] : 0;
    int v = orig;
    for (int off = 1; off < 64; off <<= 1) {
        int t = __shfl_up(v, off);
        if (lane >= off) v += t;
    }
    if (lane < nb) bs[lane] = v - orig;  // exclusive
}

__global__ __launch_bounds__(256) void scan_final(const int* __restrict__ cnt, int n,
                                                  const int* __restrict__ bsums,
                                                  int* __restrict__ offs) {
    __shared__ int tsum[256];
    int base = blockIdx.x * 4096;
    int tid = threadIdx.x;
    int local[16];
    int s = 0;
#pragma unroll
    for (int j = 0; j < 16; ++j) {
        int idx = base + tid * 16 + j;
        int v = (idx < n) ? cnt[idx] : 0;
        s += v;
        local[j] = s;
    }
    tsum[tid] = s;
    __syncthreads();
    int v = s;
    for (int off = 1; off < 256; off <<= 1) {
        int t = (tid >= off) ? tsum[tid - off] : 0;
        __syncthreads();
        v += t;
        tsum[tid] = v;
        __syncthreads();
    }
    int tpre = v - s;
    int bpre = bsums[blockIdx.x];
#pragma unroll
    for (int j = 0; j < 16; ++j) {
        int idx = base + tid * 16 + j;
        if (idx < n) offs[idx + 1] = bpre + tpre + local[j];
    }
    if (blockIdx.x == 0 && tid == 0) offs[0] = 0;
}

__global__ __launch_bounds__(256) void fill_kernel(const int* __restrict__ src,
                                                   const int* __restrict__ dst,
                                                   const float* __restrict__ w, int E,
                                                   const int* __restrict__ offs,
                                                   int* __restrict__ fill,
                                                   int* __restrict__ csr_src,
                                                   float* __restrict__ csr_w) {
    int i = blockIdx.x * 256 + threadIdx.x;
    if (i >= E) return;
    int d = dst[i];
    int slot = offs[d] + atomicAdd(&fill[d], 1);
    csr_src[slot] = src[i];
    csr_w[slot] = w[i];
}

// ---------------- degree-equalizing permutation (counting sort by total degree) ----
// Rows grouped by exact degree => within any 16-lane wave group the CSR walk has
// near-uniform trip count (kills the max-of-16 divergence waste in the fused gather).
__global__ __launch_bounds__(256) void deg_kernel(const int* __restrict__ o0,
                                                  const int* __restrict__ o1,
                                                  const int* __restrict__ o2,
                                                  int nrel, int n,
                                                  int* __restrict__ deg,
                                                  int* __restrict__ hist) {
    int i = blockIdx.x * 256 + threadIdx.x;
    if (i >= n) return;
    int d = o0[i + 1] - o0[i];
    if (nrel > 1) d += o1[i + 1] - o1[i];
    if (nrel > 2) d += o2[i + 1] - o2[i];
    if (d > 511) d = 511;
    deg[i] = d;
    atomicAdd(&hist[d], 1);
}

__global__ __launch_bounds__(512) void hist_scan(int* __restrict__ hist) {
    __shared__ int sd[512];
    int t = threadIdx.x;
    int v = hist[t];
    sd[t] = v;
    __syncthreads();
    int acc = v;
    for (int off = 1; off < 512; off <<= 1) {
        int u = (t >= off) ? sd[t - off] : 0;
        __syncthreads();
        acc += u;
        sd[t] = acc;
        __syncthreads();
    }
    hist[t] = acc - v;  // exclusive prefix
}

__global__ __launch_bounds__(256) void perm_scatter(const int* __restrict__ deg, int n,
                                                    int* __restrict__ hist,
                                                    int* __restrict__ perm) {
    int i = blockIdx.x * 256 + threadIdx.x;
    if (i >= n) return;
    int pos = atomicAdd(&hist[deg[i]], 1);
    perm[pos] = i;
}

// ---------------- f32 -> bf16 hi/lo split helpers ----------------
// hi = truncated top 16 bits (exact bf16); lo = bf16(trunc) of residual.
// a ~= hi + lo with relative error ~2^-16; dropped lo*lo term in the GEMM is
// ~2^-16 relative => result is f32-equivalent for this problem's magnitudes.
__device__ __forceinline__ unsigned pk_hi(float a, float b) {
    return (__float_as_uint(b) & 0xffff0000u) | (__float_as_uint(a) >> 16);
}
__device__ __forceinline__ float f32_trunc(float a) {
    return __uint_as_float(__float_as_uint(a) & 0xffff0000u);
}

typedef short bf16x8 __attribute__((ext_vector_type(8)));
typedef float f32x4 __attribute__((ext_vector_type(4)));

__device__ __forceinline__ bf16x8 pack_hi8(const float4& a, const float4& b) {
    union { unsigned u[4]; bf16x8 v; } r;
    r.u[0] = pk_hi(a.x, a.y);
    r.u[1] = pk_hi(a.z, a.w);
    r.u[2] = pk_hi(b.x, b.y);
    r.u[3] = pk_hi(b.z, b.w);
    return r.v;
}
__device__ __forceinline__ bf16x8 pack_lo8(const float4& a, const float4& b) {
    union { unsigned u[4]; bf16x8 v; } r;
    r.u[0] = pk_hi(a.x - f32_trunc(a.x), a.y - f32_trunc(a.y));
    r.u[1] = pk_hi(a.z - f32_trunc(a.z), a.w - f32_trunc(a.w));
    r.u[2] = pk_hi(b.x - f32_trunc(b.x), b.y - f32_trunc(b.y));
    r.u[3] = pk_hi(b.z - f32_trunc(b.z), b.w - f32_trunc(b.w));
    return r.v;
}

// ---------------- fused weight build ----------------
// Produces bf16 hi/lo planes of the concat-K B matrix, stored as a sequence of
// 64-k tiles per (layer,dst): tile t is 128n x 64k = 8192 shorts, PRE-SWIZZLED:
//   elem (n, kk) lives at tile*8192 + ((n*64 + kk) ^ ((n&7)<<3))
// so the GEMM can copy it LINEARLY into LDS and read conflict-free ds_read_b128
// with the same XOR (Guideline 21: source perm == read perm).
__global__ __launch_bounds__(256) void wt_build(const float* __restrict__ W1_l,
                                                const float* __restrict__ b1,
                                                const float* __restrict__ W1_r,
                                                const float* __restrict__ W2_l,
                                                const float* __restrict__ b2,
                                                const float* __restrict__ W2_r,
                                                unsigned short* __restrict__ WH,
                                                unsigned short* __restrict__ WL,
                                                float* __restrict__ bsum) {
    const int relsD[4][3] = {{1, 3, -1}, {0, 4, 7}, {6, -1, -1}, {2, 5, -1}};
    const int nrelD[4] = {2, 3, 1, 2};
    const int pre[4] = {0, 49152, 114688, 147456};  // elements, per-layer prefix
    int bid = blockIdx.x;
    int l = bid / 12, r = bid % 12;
    int d, s;
    if (r < 3) { d = 0; s = r; }
    else if (r < 7) { d = 1; s = r - 3; }
    else if (r < 9) { d = 2; s = r - 7; }
    else { d = 3; s = r - 9; }
    const float* Wl = l ? W2_l : W1_l;
    const float* Wr = l ? W2_r : W1_r;
    const float* bb = l ? b2 : b1;
    size_t base = (size_t)l * 196608 + pre[d];
    if (s == 0 && threadIdx.x < 128) {
        float acc = 0.f;
        for (int j = 0; j < nrelD[d]; ++j) acc += bb[relsD[d][j] * 128 + threadIdx.x];
        bsum[(l * 4 + d) * 128 + threadIdx.x] = acc;
    }
    for (int p = 0; p < 8; ++p) {
        int c = threadIdx.x + p * 256;
        int n = c >> 4, ic = (c & 15) * 8;
        float e[8];
        if (s == 0) {
#pragma unroll
            for (int q = 0; q < 8; ++q) e[q] = 0.f;
            for (int j = 0; j < nrelD[d]; ++j) {
                const float* wsrc = Wl + relsD[d][j] * 16384 + n * 128 + ic;
#pragma unroll
                for (int q = 0; q < 8; ++q) e[q] += wsrc[q];
            }
        } else {
            const float* wsrc = Wr + relsD[d][s - 1] * 16384 + n * 128 + ic;
#pragma unroll
            for (int q = 0; q < 8; ++q) e[q] = wsrc[q];
        }
        uint4 hi, lo;
        hi.x = pk_hi(e[0], e[1]); hi.y = pk_hi(e[2], e[3]);
        hi.z = pk_hi(e[4], e[5]); hi.w = pk_hi(e[6], e[7]);
        float lv[8];
#pragma unroll
        for (int q = 0; q < 8; ++q) lv[q] = e[q] - f32_trunc(e[q]);
        lo.x = pk_hi(lv[0], lv[1]); lo.y = pk_hi(lv[2], lv[3]);
        lo.z = pk_hi(lv[4], lv[5]); lo.w = pk_hi(lv[6], lv[7]);
        int tile = s * 2 + (ic >> 6);
        int kk = ic & 63;
        size_t go = base + (size_t)tile * 8192 + (size_t)(((n * 64 + kk) ^ ((n & 7) << 3)));
        *(uint4*)(WH + go) = hi;
        *(uint4*)(WL + go) = lo;
    }
}

// ---------------- per-relation CSR args for the fused GEMM ----------------
struct RelArg {
    const int* offs;    // [n_dst+1]
    const int* csr;     // src indices, CSR order
    const float* w;     // edge weights, CSR order
    const float* X;     // source-type feature rows [n_src][128]
};

// ---------------- fused gather + concat-K MFMA GEMM (degree-sorted rows) ----------
// Block handles LOGICAL rows [m0, m0+128); physical row = perm[logical].
// Sorted-by-degree rows => the 16 rows a wave walks per agg tile have ~equal
// degree (no max-of-16 divergence waste). The f=0/f=1 walks are INTERLEAVED in
// one loop (2x MLP, max(d0,d1)~d trips instead of d0+d1).
// Per-row edge order + accumulation order identical to previous rounds =>
// bitwise-identical output values (rows just land via perm).
// B staged to LDS IMMEDIATELY (load->write->barrier) so a slow-gather wave only
// delays its own MFMAs, not the whole block.
__global__ __launch_bounds__(256, 3) void gemm_fused(const float* __restrict__ Xself, int lds_,
                                                     RelArg R0, RelArg R1, RelArg R2,
                                                     const int* __restrict__ perm,
                                                     const unsigned short* __restrict__ WH,
                                                     const unsigned short* __restrict__ WL,
                                                     const float* __restrict__ bias,
                                                     float* __restrict__ Y, int ldy,
                                                     int M, int K, int relu) {
    __shared__ unsigned short sBh[8192];  // one 64-k B tile, hi plane, swizzled
    __shared__ unsigned short sBl[8192];  // lo plane
    int tid = threadIdx.x;
    int lane = tid & 63;
    int wave = tid >> 6;  // 0..3
    int m0 = blockIdx.x * 128;
    int ln = lane & 15;
    int kq = (lane >> 4) * 8;   // lane's k-offset within a 32-k step
    int rowA = wave * 32 + ln;  // logical tile-row for f=0; f=1 adds 16

    int gmL0 = m0 + rowA, gmL1 = gmL0 + 16;
    int pr0 = (gmL0 < M) ? perm[gmL0] : -1;  // physical rows
    int pr1 = (gmL1 < M) ? perm[gmL1] : -1;

    f32x4 acc[2][8] = {};  // [m-frag][n-frag]

    float bv[8];
#pragma unroll
    for (int g = 0; g < 8; ++g) bv[g] = bias[g * 16 + ln];

    int nt = K >> 6;
    for (int t = 0; t < nt; ++t) {
        const unsigned short* wht = WH + (size_t)t * 8192;
        const unsigned short* wlt = WL + (size_t)t * 8192;
        __syncthreads();  // all waves done reading previous tile's LDS
        // ---- stage B tile: global -> reg -> LDS (linear copy of swizzled tile)
        uint4 rh[4], rl[4];
#pragma unroll
        for (int p = 0; p < 4; ++p) {
            rh[p] = *(const uint4*)(wht + (size_t)(tid + p * 256) * 8);
            rl[p] = *(const uint4*)(wlt + (size_t)(tid + p * 256) * 8);
        }
#pragma unroll
        for (int p = 0; p < 4; ++p) {
            *(uint4*)&sBh[(size_t)(tid + p * 256) * 8] = rh[p];
            *(uint4*)&sBl[(size_t)(tid + p * 256) * 8] = rl[p];
        }
        __syncthreads();  // B tile staged; gathers below overlap other waves' MFMAs
        // ---- produce A fragments: Af[(f*2+ks)*2+half] covers cols kq+ks*32+half*4..+4
        float4 Af[8];
        if (t < 2) {
            // self tile: stream physical rows
            int kc0 = t * 64;
#pragma unroll
            for (int f = 0; f < 2; ++f) {
                int prf = f ? pr1 : pr0;
#pragma unroll
                for (int ks = 0; ks < 2; ++ks) {
                    float4 v0 = {0.f, 0.f, 0.f, 0.f}, v1 = {0.f, 0.f, 0.f, 0.f};
                    if (prf >= 0) {
                        const float* pr_ = Xself + (size_t)prf * lds_ + kc0 + kq;
                        v0 = *(const float4*)(pr_ + ks * 32);
                        v1 = *(const float4*)(pr_ + ks * 32 + 4);
                    }
                    Af[(f * 2 + ks) * 2 + 0] = v0;
                    Af[(f * 2 + ks) * 2 + 1] = v1;
                }
            }
        } else {
            // agg tile: fused CSR gather-mean, f=0/f=1 interleaved
            int r = (t - 2) >> 1;
            int kc0r = ((t - 2) & 1) * 64;
            RelArg R = (r == 0) ? R0 : ((r == 1) ? R1 : R2);
            float4 z = {0.f, 0.f, 0.f, 0.f};
#pragma unroll
            for (int j = 0; j < 8; ++j) Af[j] = z;
            int b0 = 0, e0 = 0, b1 = 0, e1 = 0;
            if (pr0 >= 0) { b0 = R.offs[pr0]; e0 = R.offs[pr0 + 1]; }
            if (pr1 >= 0) { b1 = R.offs[pr1]; e1 = R.offs[pr1 + 1]; }
            int i0 = b0, i1 = b1;
            int s0 = 0, s1 = 0;
            float w0v = 0.f, w1v = 0.f;
            if (i0 < e0) { s0 = R.csr[i0]; w0v = R.w[i0]; }
            if (i1 < e1) { s1 = R.csr[i1]; w1v = R.w[i1]; }
            while (i0 < e0 || i1 < e1) {
                bool a0 = i0 < e0, a1 = i1 < e1;
                float4 u0, u1, u2, u3, q0, q1, q2, q3;
                if (a0) {
                    const float* xp = R.X + (size_t)s0 * 128 + kc0r + kq;
                    u0 = *(const float4*)(xp + 0);
                    u1 = *(const float4*)(xp + 4);
                    u2 = *(const float4*)(xp + 32);
                    u3 = *(const float4*)(xp + 36);
                }
                if (a1) {
                    const float* xp = R.X + (size_t)s1 * 128 + kc0r + kq;
                    q0 = *(const float4*)(xp + 0);
                    q1 = *(const float4*)(xp + 4);
                    q2 = *(const float4*)(xp + 32);
                    q3 = *(const float4*)(xp + 36);
                }
                if (a0) ++i0;
                if (a1) ++i1;
                int sn0 = s0, sn1 = s1;
                float wn0 = w0v, wn1 = w1v;
                if (i0 < e0) { sn0 = R.csr[i0]; wn0 = R.w[i0]; }  // prefetch under gather
                if (i1 < e1) { sn1 = R.csr[i1]; wn1 = R.w[i1]; }
                if (a0) {
                    Af[0].x += w0v * u0.x; Af[0].y += w0v * u0.y; Af[0].z += w0v * u0.z; Af[0].w += w0v * u0.w;
                    Af[1].x += w0v * u1.x; Af[1].y += w0v * u1.y; Af[1].z += w0v * u1.z; Af[1].w += w0v * u1.w;
                    Af[2].x += w0v * u2.x; Af[2].y += w0v * u2.y; Af[2].z += w0v * u2.z; Af[2].w += w0v * u2.w;
                    Af[3].x += w0v * u3.x; Af[3].y += w0v * u3.y; Af[3].z += w0v * u3.z; Af[3].w += w0v * u3.w;
                }
                if (a1) {
                    Af[4].x += w1v * q0.x; Af[4].y += w1v * q0.y; Af[4].z += w1v * q0.z; Af[4].w += w1v * q0.w;
                    Af[5].x += w1v * q1.x; Af[5].y += w1v * q1.y; Af[5].z += w1v * q1.z; Af[5].w += w1v * q1.w;
                    Af[6].x += w1v * q2.x; Af[6].y += w1v * q2.y; Af[6].z += w1v * q2.z; Af[6].w += w1v * q2.w;
                    Af[7].x += w1v * q3.x; Af[7].y += w1v * q3.y; Af[7].z += w1v * q3.z; Af[7].w += w1v * q3.w;
                }
                s0 = sn0; w0v = wn0; s1 = sn1; w1v = wn1;
            }
            if (e0 > b0) {
                float inv = 1.f / (float)(e0 - b0);
#pragma unroll
                for (int j = 0; j < 4; ++j) {
                    Af[j].x *= inv; Af[j].y *= inv; Af[j].z *= inv; Af[j].w *= inv;
                }
            }
            if (e1 > b1) {
                float inv = 1.f / (float)(e1 - b1);
#pragma unroll
                for (int j = 4; j < 8; ++j) {
                    Af[j].x *= inv; Af[j].y *= inv; Af[j].z *= inv; Af[j].w *= inv;
                }
            }
        }
        // ---- pack A to bf16 hi/lo in-reg
        bf16x8 ah[4], al[4];
#pragma unroll
        for (int j = 0; j < 4; ++j) {
            ah[j] = pack_hi8(Af[j * 2], Af[j * 2 + 1]);
            al[j] = pack_lo8(Af[j * 2], Af[j * 2 + 1]);
        }
        // ---- compute: 2 k-steps of 32; B frags from LDS (swizzled, conflict-free)
#pragma unroll
        for (int ks = 0; ks < 2; ++ks) {
#pragma unroll
            for (int g = 0; g < 8; ++g) {
                int sidx = ((g * 16 + ln) * 64 + ks * 32 + kq) ^ ((ln & 7) << 3);
                bf16x8 bh = *(const bf16x8*)&sBh[sidx];
                bf16x8 bl = *(const bf16x8*)&sBl[sidx];
#pragma unroll
                for (int f = 0; f < 2; ++f) {
                    acc[f][g] = __builtin_amdgcn_mfma_f32_16x16x32_bf16(ah[f * 2 + ks], bh, acc[f][g], 0, 0, 0);
                    acc[f][g] = __builtin_amdgcn_mfma_f32_16x16x32_bf16(ah[f * 2 + ks], bl, acc[f][g], 0, 0, 0);
                    acc[f][g] = __builtin_amdgcn_mfma_f32_16x16x32_bf16(al[f * 2 + ks], bh, acc[f][g], 0, 0, 0);
                }
            }
        }
    }
    // ---- epilogue: C/D layout col=lane&15, row=(lane>>4)*4+reg; rows via perm
    int rbL = m0 + wave * 32 + (lane >> 4) * 4;
#pragma unroll
    for (int f = 0; f < 2; ++f) {
#pragma unroll
        for (int r = 0; r < 4; ++r) {
            int rowL = rbL + f * 16 + r;
            if (rowL >= M) continue;
            int rowP = perm[rowL];
            float* yr = Y + (size_t)rowP * ldy + ln;
#pragma unroll
            for (int g = 0; g < 8; ++g) {
                float v = acc[f][g][r] + bv[g];
                if (relu) v = fmaxf(v, 0.f);
                yr[g * 16] = v;
            }
        }
    }
}

// ---------------- host orchestration ----------------
extern "C" void kernel_launch(void* const* d_in, const int* in_sizes, int n_in,
                              void* d_out, int out_size, void* d_ws, size_t ws_size,
                              hipStream_t stream) {
    const float* emb[4] = {(const float*)d_in[0], (const float*)d_in[1],
                           (const float*)d_in[2], (const float*)d_in[3]};
    const float* W1_l = (const float*)d_in[4];
    const float* b1 = (const float*)d_in[5];
    const float* W1_r = (const float*)d_in[6];
    const float* W2_l = (const float*)d_in[7];
    const float* b2 = (const float*)d_in[8];
    const float* W2_r = (const float*)d_in[9];
    const float* ew[8];
    for (int i = 0; i < 8; ++i) ew[i] = (const float*)d_in[10 + i];
    const int* ei_buys = (const int*)d_in[18];
    const int* ei_sea = (const int*)d_in[19];
    const int* ei_mat = (const int*)d_in[20];
    const int* ei_in = (const int*)d_in[21];

    const int NT[4] = {NUSER, NPROD, NCAT, NQRY};
    const int rowOff[4] = {0, NUSER, NUSER + NPROD, NUSER + NPROD + NCAT};
    const int nrelD[4] = {2, 3, 1, 2};
    const int wtPre[4] = {0, 49152, 114688, 147456};

    struct RelT { int s, d, slot, E; const int* src; const int* dst; const float* w; };
    // slot assignment must match wt_build relsD: user{1,3} product{0,4,7} cat{6} query{2,5}
    RelT rel[8] = {
        {0, 1, 0, EBUYS,   ei_buys,          ei_buys + EBUYS,  ew[0]},  // t0
        {1, 0, 0, EBUYS,   ei_buys + EBUYS,  ei_buys,          ew[1]},  // t1
        {0, 3, 0, ESEARCH, ei_sea,           ei_sea + ESEARCH, ew[2]},  // t2
        {3, 0, 1, ESEARCH, ei_sea + ESEARCH, ei_sea,           ew[3]},  // t3
        {3, 1, 1, EMATCH,  ei_mat,           ei_mat + EMATCH,  ew[4]},  // t4
        {1, 3, 1, EMATCH,  ei_mat + EMATCH,  ei_mat,           ew[5]},  // t5
        {1, 2, 0, EIN,     ei_in,            ei_in + EIN,      ew[6]},  // t6
        {2, 1, 2, EIN,     ei_in + EIN,      ei_in,            ew[7]},  // t7
    };

    // ---- workspace carve ----
    char* p = (char*)d_ws;
    auto carve = [&](size_t bytes) {
        char* r = p;
        p += (bytes + 255) & ~(size_t)255;
        return r;
    };
    int* offs[8];
    for (int t = 0; t < 8; ++t) offs[t] = (int*)carve(((size_t)NT[rel[t].d] + 1) * 4);
    size_t fillTot = 0;
    for (int t = 0; t < 8; ++t) fillTot += (size_t)NT[rel[t].d];
    int* fillBase = (int*)carve(fillTot * 4);
    int* fill[8];
    {
        size_t o = 0;
        for (int t = 0; t < 8; ++t) { fill[t] = fillBase + o; o += NT[rel[t].d]; }
    }
    size_t Etot = 0;
    int eoff[8];
    for (int t = 0; t < 8; ++t) { eoff[t] = (int)Etot; Etot += rel[t].E; }
    int* csr_src = (int*)carve(Etot * 4);
    float* csr_w = (float*)carve(Etot * 4);
    int* bsums = (int*)carve(64 * 4);
    unsigned short* WH = (unsigned short*)carve((size_t)2 * 196608 * 2);
    unsigned short* WL = (unsigned short*)carve((size_t)2 * 196608 * 2);
    float* bsum = (float*)carve((size_t)8 * 128 * 4);
    // degree-sort scratch + per-type permutations
    int* degbuf = (int*)carve((size_t)NUSER * 4);
    int* hist = (int*)carve(512 * 4);
    int* perm[4];
    for (int d = 0; d < 4; ++d) perm[d] = (int*)carve((size_t)NT[d] * 4);
    // layer-0 hidden state h (all 4 types stacked): 352k x 128 f32 = ~180 MB
    float* hbuf = (float*)carve((size_t)(NUSER + NPROD + NCAT + NQRY) * 128 * 4);

    // ---- CSR build (once, reused by both layers) ----
    hipMemsetAsync(fillBase, 0, fillTot * 4, stream);
    for (int t = 0; t < 8; ++t)
        count_kernel<<<(rel[t].E + 255) / 256, 256, 0, stream>>>(rel[t].dst, rel[t].E, fill[t]);
    for (int t = 0; t < 8; ++t) {
        int n = NT[rel[t].d];
        int nb = (n + 4095) / 4096;
        scan_partial<<<nb, 256, 0, stream>>>(fill[t], n, bsums);
        scan_bsums<<<1, 64, 0, stream>>>(bsums, nb);
        scan_final<<<nb, 256, 0, stream>>>(fill[t], n, bsums, offs[t]);
    }
    hipMemsetAsync(fillBase, 0, fillTot * 4, stream);
    for (int t = 0; t < 8; ++t)
        fill_kernel<<<(rel[t].E + 255) / 256, 256, 0, stream>>>(
            rel[t].src, rel[t].dst, rel[t].w, rel[t].E, offs[t], fill[t],
            csr_src + eoff[t], csr_w + eoff[t]);

    // ---- degree-equalizing permutation per dst type ----
    for (int d = 0; d < 4; ++d) {
        const int* od[3] = {nullptr, nullptr, nullptr};
        int nr = 0;
        for (int t = 0; t < 8; ++t)
            if (rel[t].d == d) od[rel[t].slot] = offs[t], ++nr;
        int n = NT[d];
        hipMemsetAsync(hist, 0, 512 * 4, stream);
        deg_kernel<<<(n + 255) / 256, 256, 0, stream>>>(
            od[0], nr > 1 ? od[1] : od[0], nr > 2 ? od[2] : od[0], nr, n, degbuf, hist);
        hist_scan<<<1, 512, 0, stream>>>(hist);
        perm_scatter<<<(n + 255) / 256, 256, 0, stream>>>(degbuf, n, hist, perm[d]);
    }

    // ---- fused split-bf16 weights (tiled + swizzled) + summed bias ----
    wt_build<<<24, 256, 0, stream>>>(W1_l, b1, W1_r, W2_l, b2, W2_r, WH, WL, bsum);

    float* dout = (float*)d_out;

    // ---- two layers; layer 0 writes hbuf, layer 1 gathers from hbuf, writes d_out ----
    for (int layer = 0; layer < 2; ++layer) {
        for (int d = 0; d < 4; ++d) {
            int n = NT[d];
            const float* self = layer == 0 ? emb[d] : hbuf + (size_t)rowOff[d] * 128;
            float* Yd = (layer == 0 ? hbuf : dout) + (size_t)rowOff[d] * 128;
            RelArg RA[3];
            int nr = 0;
            for (int t = 0; t < 8; ++t) {
                if (rel[t].d != d) continue;
                RelArg a;
                a.offs = offs[t];
                a.csr = csr_src + eoff[t];
                a.w = csr_w + eoff[t];
                a.X = layer == 0 ? emb[rel[t].s] : hbuf + (size_t)rowOff[rel[t].s] * 128;
                RA[rel[t].slot] = a;
                ++nr;
            }
            for (int s2 = nr; s2 < 3; ++s2) RA[s2] = RA[0];  // unused slots (never read)
            size_t woff = (size_t)layer * 196608 + wtPre[d];
            gemm_fused<<<(n + 127) / 128, 256, 0, stream>>>(
                self, 128, RA[0], RA[1], RA[2], perm[d],
                WH + woff, WL + woff, bsum + (size_t)(layer * 4 + d) * 128,
                Yd, 128, n, (1 + nrelD[d]) * 128,
                layer == 0 ? 1 : 0);
        }
    }
}

// Round 7
// 2835.363 us; speedup vs baseline: 1.9140x; 1.9140x over previous
//
#include <hip/hip_runtime.h>

// ---------------- problem constants ----------------
#define NUSER 200000
#define NPROD 100000
#define NCAT    2000
#define NQRY   50000
#define EBUYS  500000
#define ESEARCH 300000
#define EMATCH  300000
#define EIN     100000

// type ids: 0=user 1=product 2=category 3=query
// relations t=0..7 (weight-stack index):
//  t0 user->product, t1 product->user, t2 user->query, t3 query->user,
//  t4 query->product, t5 product->query, t6 product->category, t7 category->product
// per-dst relation slots (must match wt_build's relsD):
//  user: {t1,t3}  product: {t0,t4,t7}  category: {t6}  query: {t2,t5}

// ---------------- CSR build ----------------
__global__ __launch_bounds__(256) void count_kernel(const int* __restrict__ dst, int E,
                                                    int* __restrict__ cnt) {
    int i = blockIdx.x * 256 + threadIdx.x;
    if (i < E) atomicAdd(&cnt[dst[i]], 1);
}

__global__ __launch_bounds__(256) void scan_partial(const int* __restrict__ cnt, int n,
                                                    int* __restrict__ bsums) {
    __shared__ int sd[256];
    int base = blockIdx.x * 4096;
    int s = 0;
    for (int j = threadIdx.x; j < 4096; j += 256) {
        int idx = base + j;
        s += (idx < n) ? cnt[idx] : 0;
    }
    sd[threadIdx.x] = s;
    __syncthreads();
    for (int st = 128; st > 0; st >>= 1) {
        if (threadIdx.x < st) sd[threadIdx.x] += sd[threadIdx.x + st];
        __syncthreads();
    }
    if (threadIdx.x == 0) bsums[blockIdx.x] = sd[0];
}

__global__ __launch_bounds__(64) void scan_bsums(int* __restrict__ bs, int nb) {
    int lane = threadIdx.x;
    int orig = (lane < nb) ? bs[lane] : 0;
    int v = orig;
    for (int off = 1; off < 64; off <<= 1) {
        int t = __shfl_up(v, off);
        if (lane >= off) v += t;
    }
    if (lane < nb) bs[lane] = v - orig;  // exclusive
}

__global__ __launch_bounds__(256) void scan_final(const int* __restrict__ cnt, int n,
                                                  const int* __restrict__ bsums,
                                                  int* __restrict__ offs) {
    __shared__ int tsum[256];
    int base = blockIdx.x * 4096;
    int tid = threadIdx.x;
    int local[16];
    int s = 0;
#pragma unroll
    for (int j = 0; j < 16; ++j) {
        int idx = base + tid * 16 + j;
        int v = (idx < n) ? cnt[idx] : 0;
        s += v;
        local[j] = s;
    }
    tsum[tid] = s;
    __syncthreads();
    int v = s;
    for (int off = 1; off < 256; off <<= 1) {
        int t = (tid >= off) ? tsum[tid - off] : 0;
        __syncthreads();
        v += t;
        tsum[tid] = v;
        __syncthreads();
    }
    int tpre = v - s;
    int bpre = bsums[blockIdx.x];
#pragma unroll
    for (int j = 0; j < 16; ++j) {
        int idx = base + tid * 16 + j;
        if (idx < n) offs[idx + 1] = bpre + tpre + local[j];
    }
    if (blockIdx.x == 0 && tid == 0) offs[0] = 0;
}

__global__ __launch_bounds__(256) void fill_kernel(const int* __restrict__ src,
                                                   const int* __restrict__ dst,
                                                   const float* __restrict__ w, int E,
                                                   const int* __restrict__ offs,
                                                   int* __restrict__ fill,
                                                   int* __restrict__ csr_src,
                                                   float* __restrict__ csr_w) {
    int i = blockIdx.x * 256 + threadIdx.x;
    if (i >= E) return;
    int d = dst[i];
    int slot = offs[d] + atomicAdd(&fill[d], 1);
    csr_src[slot] = src[i];
    csr_w[slot] = w[i];
}

// ---------------- degree-equalizing permutation (counting sort by total degree) ----
// G12-compliant: LDS histogram per block + ONE global atomic per (block, touched
// bin) — ~12 global atomics/block instead of 256 (round-6's naive version was
// 200k device atomics on ~12 addresses = 808 us; this is ~6 us).
// Order within a degree group is race-determined, but perm only needs to be a
// bijection grouping equal degrees — per-row outputs are independent => results
// identical.
__global__ __launch_bounds__(256) void deg_kernel(const int* __restrict__ o0,
                                                  const int* __restrict__ o1,
                                                  const int* __restrict__ o2,
                                                  int nrel, int n,
                                                  int* __restrict__ deg,
                                                  int* __restrict__ hist) {
    __shared__ int h[512];
    for (int j = threadIdx.x; j < 512; j += 256) h[j] = 0;
    __syncthreads();
    int i = blockIdx.x * 256 + threadIdx.x;
    if (i < n) {
        int d = o0[i + 1] - o0[i];
        if (nrel > 1) d += o1[i + 1] - o1[i];
        if (nrel > 2) d += o2[i + 1] - o2[i];
        if (d > 511) d = 511;
        deg[i] = d;
        atomicAdd(&h[d], 1);  // LDS atomic
    }
    __syncthreads();
    for (int j = threadIdx.x; j < 512; j += 256) {
        int c = h[j];
        if (c) atomicAdd(&hist[j], c);  // one global atomic per touched bin
    }
}

__global__ __launch_bounds__(512) void hist_scan(int* __restrict__ hist) {
    __shared__ int sd[512];
    int t = threadIdx.x;
    int v = hist[t];
    sd[t] = v;
    __syncthreads();
    int acc = v;
    for (int off = 1; off < 512; off <<= 1) {
        int u = (t >= off) ? sd[t - off] : 0;
        __syncthreads();
        acc += u;
        sd[t] = acc;
        __syncthreads();
    }
    hist[t] = acc - v;  // exclusive prefix
}

__global__ __launch_bounds__(256) void perm_scatter(const int* __restrict__ deg, int n,
                                                    int* __restrict__ hist,
                                                    int* __restrict__ perm) {
    __shared__ int h[512];
    __shared__ int base[512];
    for (int j = threadIdx.x; j < 512; j += 256) h[j] = 0;
    __syncthreads();
    int i = blockIdx.x * 256 + threadIdx.x;
    int d = 0, lr = 0;
    if (i < n) {
        d = deg[i];
        lr = atomicAdd(&h[d], 1);  // LDS: local rank within block
    }
    __syncthreads();
    for (int j = threadIdx.x; j < 512; j += 256) {
        int c = h[j];
        if (c) base[j] = atomicAdd(&hist[j], c);  // one global atomic per touched bin
    }
    __syncthreads();
    if (i < n) perm[base[d] + lr] = i;
}

// ---------------- f32 -> bf16 hi/lo split helpers ----------------
// hi = truncated top 16 bits (exact bf16); lo = bf16(trunc) of residual.
// a ~= hi + lo with relative error ~2^-16; dropped lo*lo term in the GEMM is
// ~2^-16 relative => result is f32-equivalent for this problem's magnitudes.
__device__ __forceinline__ unsigned pk_hi(float a, float b) {
    return (__float_as_uint(b) & 0xffff0000u) | (__float_as_uint(a) >> 16);
}
__device__ __forceinline__ float f32_trunc(float a) {
    return __uint_as_float(__float_as_uint(a) & 0xffff0000u);
}

typedef short bf16x8 __attribute__((ext_vector_type(8)));
typedef float f32x4 __attribute__((ext_vector_type(4)));

__device__ __forceinline__ bf16x8 pack_hi8(const float4& a, const float4& b) {
    union { unsigned u[4]; bf16x8 v; } r;
    r.u[0] = pk_hi(a.x, a.y);
    r.u[1] = pk_hi(a.z, a.w);
    r.u[2] = pk_hi(b.x, b.y);
    r.u[3] = pk_hi(b.z, b.w);
    return r.v;
}
__device__ __forceinline__ bf16x8 pack_lo8(const float4& a, const float4& b) {
    union { unsigned u[4]; bf16x8 v; } r;
    r.u[0] = pk_hi(a.x - f32_trunc(a.x), a.y - f32_trunc(a.y));
    r.u[1] = pk_hi(a.z - f32_trunc(a.z), a.w - f32_trunc(a.w));
    r.u[2] = pk_hi(b.x - f32_trunc(b.x), b.y - f32_trunc(b.y));
    r.u[3] = pk_hi(b.z - f32_trunc(b.z), b.w - f32_trunc(b.w));
    return r.v;
}

// ---------------- fused weight build ----------------
// Produces bf16 hi/lo planes of the concat-K B matrix, stored as a sequence of
// 64-k tiles per (layer,dst): tile t is 128n x 64k = 8192 shorts, PRE-SWIZZLED:
//   elem (n, kk) lives at tile*8192 + ((n*64 + kk) ^ ((n&7)<<3))
// so the GEMM can copy it LINEARLY into LDS and read conflict-free ds_read_b128
// with the same XOR (Guideline 21: source perm == read perm).
__global__ __launch_bounds__(256) void wt_build(const float* __restrict__ W1_l,
                                                const float* __restrict__ b1,
                                                const float* __restrict__ W1_r,
                                                const float* __restrict__ W2_l,
                                                const float* __restrict__ b2,
                                                const float* __restrict__ W2_r,
                                                unsigned short* __restrict__ WH,
                                                unsigned short* __restrict__ WL,
                                                float* __restrict__ bsum) {
    const int relsD[4][3] = {{1, 3, -1}, {0, 4, 7}, {6, -1, -1}, {2, 5, -1}};
    const int nrelD[4] = {2, 3, 1, 2};
    const int pre[4] = {0, 49152, 114688, 147456};  // elements, per-layer prefix
    int bid = blockIdx.x;
    int l = bid / 12, r = bid % 12;
    int d, s;
    if (r < 3) { d = 0; s = r; }
    else if (r < 7) { d = 1; s = r - 3; }
    else if (r < 9) { d = 2; s = r - 7; }
    else { d = 3; s = r - 9; }
    const float* Wl = l ? W2_l : W1_l;
    const float* Wr = l ? W2_r : W1_r;
    const float* bb = l ? b2 : b1;
    size_t base = (size_t)l * 196608 + pre[d];
    if (s == 0 && threadIdx.x < 128) {
        float acc = 0.f;
        for (int j = 0; j < nrelD[d]; ++j) acc += bb[relsD[d][j] * 128 + threadIdx.x];
        bsum[(l * 4 + d) * 128 + threadIdx.x] = acc;
    }
    for (int p = 0; p < 8; ++p) {
        int c = threadIdx.x + p * 256;
        int n = c >> 4, ic = (c & 15) * 8;
        float e[8];
        if (s == 0) {
#pragma unroll
            for (int q = 0; q < 8; ++q) e[q] = 0.f;
            for (int j = 0; j < nrelD[d]; ++j) {
                const float* wsrc = Wl + relsD[d][j] * 16384 + n * 128 + ic;
#pragma unroll
                for (int q = 0; q < 8; ++q) e[q] += wsrc[q];
            }
        } else {
            const float* wsrc = Wr + relsD[d][s - 1] * 16384 + n * 128 + ic;
#pragma unroll
            for (int q = 0; q < 8; ++q) e[q] = wsrc[q];
        }
        uint4 hi, lo;
        hi.x = pk_hi(e[0], e[1]); hi.y = pk_hi(e[2], e[3]);
        hi.z = pk_hi(e[4], e[5]); hi.w = pk_hi(e[6], e[7]);
        float lv[8];
#pragma unroll
        for (int q = 0; q < 8; ++q) lv[q] = e[q] - f32_trunc(e[q]);
        lo.x = pk_hi(lv[0], lv[1]); lo.y = pk_hi(lv[2], lv[3]);
        lo.z = pk_hi(lv[4], lv[5]); lo.w = pk_hi(lv[6], lv[7]);
        int tile = s * 2 + (ic >> 6);
        int kk = ic & 63;
        size_t go = base + (size_t)tile * 8192 + (size_t)(((n * 64 + kk) ^ ((n & 7) << 3)));
        *(uint4*)(WH + go) = hi;
        *(uint4*)(WL + go) = lo;
    }
}

// ---------------- per-relation CSR args for the fused GEMM ----------------
struct RelArg {
    const int* offs;    // [n_dst+1]
    const int* csr;     // src indices, CSR order
    const float* w;     // edge weights, CSR order
    const float* X;     // source-type feature rows [n_src][128]
};

// ---------------- fused gather + concat-K MFMA GEMM (degree-sorted rows) ----------
// Block handles LOGICAL rows [m0, m0+128); physical row = perm[logical].
// Sorted-by-degree rows => the 16 rows a wave walks per agg tile have ~equal
// degree (no max-of-16 divergence waste). The f=0/f=1 walks are INTERLEAVED in
// one loop (2x MLP, max(d0,d1)~d trips instead of d0+d1).
// Per-row edge order + accumulation order identical to previous rounds =>
// bitwise-identical output values (rows just land via perm).
// B staged to LDS IMMEDIATELY (load->write->barrier) so a slow-gather wave only
// delays its own MFMAs, not the whole block.
__global__ __launch_bounds__(256, 3) void gemm_fused(const float* __restrict__ Xself, int lds_,
                                                     RelArg R0, RelArg R1, RelArg R2,
                                                     const int* __restrict__ perm,
                                                     const unsigned short* __restrict__ WH,
                                                     const unsigned short* __restrict__ WL,
                                                     const float* __restrict__ bias,
                                                     float* __restrict__ Y, int ldy,
                                                     int M, int K, int relu) {
    __shared__ unsigned short sBh[8192];  // one 64-k B tile, hi plane, swizzled
    __shared__ unsigned short sBl[8192];  // lo plane
    int tid = threadIdx.x;
    int lane = tid & 63;
    int wave = tid >> 6;  // 0..3
    int m0 = blockIdx.x * 128;
    int ln = lane & 15;
    int kq = (lane >> 4) * 8;   // lane's k-offset within a 32-k step
    int rowA = wave * 32 + ln;  // logical tile-row for f=0; f=1 adds 16

    int gmL0 = m0 + rowA, gmL1 = gmL0 + 16;
    int pr0 = (gmL0 < M) ? perm[gmL0] : -1;  // physical rows
    int pr1 = (gmL1 < M) ? perm[gmL1] : -1;

    f32x4 acc[2][8] = {};  // [m-frag][n-frag]

    float bv[8];
#pragma unroll
    for (int g = 0; g < 8; ++g) bv[g] = bias[g * 16 + ln];

    int nt = K >> 6;
    for (int t = 0; t < nt; ++t) {
        const unsigned short* wht = WH + (size_t)t * 8192;
        const unsigned short* wlt = WL + (size_t)t * 8192;
        __syncthreads();  // all waves done reading previous tile's LDS
        // ---- stage B tile: global -> reg -> LDS (linear copy of swizzled tile)
        uint4 rh[4], rl[4];
#pragma unroll
        for (int p = 0; p < 4; ++p) {
            rh[p] = *(const uint4*)(wht + (size_t)(tid + p * 256) * 8);
            rl[p] = *(const uint4*)(wlt + (size_t)(tid + p * 256) * 8);
        }
#pragma unroll
        for (int p = 0; p < 4; ++p) {
            *(uint4*)&sBh[(size_t)(tid + p * 256) * 8] = rh[p];
            *(uint4*)&sBl[(size_t)(tid + p * 256) * 8] = rl[p];
        }
        __syncthreads();  // B tile staged; gathers below overlap other waves' MFMAs
        // ---- produce A fragments: Af[(f*2+ks)*2+half] covers cols kq+ks*32+half*4..+4
        float4 Af[8];
        if (t < 2) {
            // self tile: stream physical rows
            int kc0 = t * 64;
#pragma unroll
            for (int f = 0; f < 2; ++f) {
                int prf = f ? pr1 : pr0;
#pragma unroll
                for (int ks = 0; ks < 2; ++ks) {
                    float4 v0 = {0.f, 0.f, 0.f, 0.f}, v1 = {0.f, 0.f, 0.f, 0.f};
                    if (prf >= 0) {
                        const float* pr_ = Xself + (size_t)prf * lds_ + kc0 + kq;
                        v0 = *(const float4*)(pr_ + ks * 32);
                        v1 = *(const float4*)(pr_ + ks * 32 + 4);
                    }
                    Af[(f * 2 + ks) * 2 + 0] = v0;
                    Af[(f * 2 + ks) * 2 + 1] = v1;
                }
            }
        } else {
            // agg tile: fused CSR gather-mean, f=0/f=1 interleaved
            int r = (t - 2) >> 1;
            int kc0r = ((t - 2) & 1) * 64;
            RelArg R = (r == 0) ? R0 : ((r == 1) ? R1 : R2);
            float4 z = {0.f, 0.f, 0.f, 0.f};
#pragma unroll
            for (int j = 0; j < 8; ++j) Af[j] = z;
            int b0 = 0, e0 = 0, b1 = 0, e1 = 0;
            if (pr0 >= 0) { b0 = R.offs[pr0]; e0 = R.offs[pr0 + 1]; }
            if (pr1 >= 0) { b1 = R.offs[pr1]; e1 = R.offs[pr1 + 1]; }
            int i0 = b0, i1 = b1;
            int s0 = 0, s1 = 0;
            float w0v = 0.f, w1v = 0.f;
            if (i0 < e0) { s0 = R.csr[i0]; w0v = R.w[i0]; }
            if (i1 < e1) { s1 = R.csr[i1]; w1v = R.w[i1]; }
            while (i0 < e0 || i1 < e1) {
                bool a0 = i0 < e0, a1 = i1 < e1;
                float4 u0, u1, u2, u3, q0, q1, q2, q3;
                if (a0) {
                    const float* xp = R.X + (size_t)s0 * 128 + kc0r + kq;
                    u0 = *(const float4*)(xp + 0);
                    u1 = *(const float4*)(xp + 4);
                    u2 = *(const float4*)(xp + 32);
                    u3 = *(const float4*)(xp + 36);
                }
                if (a1) {
                    const float* xp = R.X + (size_t)s1 * 128 + kc0r + kq;
                    q0 = *(const float4*)(xp + 0);
                    q1 = *(const float4*)(xp + 4);
                    q2 = *(const float4*)(xp + 32);
                    q3 = *(const float4*)(xp + 36);
                }
                if (a0) ++i0;
                if (a1) ++i1;
                int sn0 = s0, sn1 = s1;
                float wn0 = w0v, wn1 = w1v;
                if (i0 < e0) { sn0 = R.csr[i0]; wn0 = R.w[i0]; }  // prefetch under gather
                if (i1 < e1) { sn1 = R.csr[i1]; wn1 = R.w[i1]; }
                if (a0) {
                    Af[0].x += w0v * u0.x; Af[0].y += w0v * u0.y; Af[0].z += w0v * u0.z; Af[0].w += w0v * u0.w;
                    Af[1].x += w0v * u1.x; Af[1].y += w0v * u1.y; Af[1].z += w0v * u1.z; Af[1].w += w0v * u1.w;
                    Af[2].x += w0v * u2.x; Af[2].y += w0v * u2.y; Af[2].z += w0v * u2.z; Af[2].w += w0v * u2.w;
                    Af[3].x += w0v * u3.x; Af[3].y += w0v * u3.y; Af[3].z += w0v * u3.z; Af[3].w += w0v * u3.w;
                }
                if (a1) {
                    Af[4].x += w1v * q0.x; Af[4].y += w1v * q0.y; Af[4].z += w1v * q0.z; Af[4].w += w1v * q0.w;
                    Af[5].x += w1v * q1.x; Af[5].y += w1v * q1.y; Af[5].z += w1v * q1.z; Af[5].w += w1v * q1.w;
                    Af[6].x += w1v * q2.x; Af[6].y += w1v * q2.y; Af[6].z += w1v * q2.z; Af[6].w += w1v * q2.w;
                    Af[7].x += w1v * q3.x; Af[7].y += w1v * q3.y; Af[7].z += w1v * q3.z; Af[7].w += w1v * q3.w;
                }
                s0 = sn0; w0v = wn0; s1 = sn1; w1v = wn1;
            }
            if (e0 > b0) {
                float inv = 1.f / (float)(e0 - b0);
#pragma unroll
                for (int j = 0; j < 4; ++j) {
                    Af[j].x *= inv; Af[j].y *= inv; Af[j].z *= inv; Af[j].w *= inv;
                }
            }
            if (e1 > b1) {
                float inv = 1.f / (float)(e1 - b1);
#pragma unroll
                for (int j = 4; j < 8; ++j) {
                    Af[j].x *= inv; Af[j].y *= inv; Af[j].z *= inv; Af[j].w *= inv;
                }
            }
        }
        // ---- pack A to bf16 hi/lo in-reg
        bf16x8 ah[4], al[4];
#pragma unroll
        for (int j = 0; j < 4; ++j) {
            ah[j] = pack_hi8(Af[j * 2], Af[j * 2 + 1]);
            al[j] = pack_lo8(Af[j * 2], Af[j * 2 + 1]);
        }
        // ---- compute: 2 k-steps of 32; B frags from LDS (swizzled, conflict-free)
#pragma unroll
        for (int ks = 0; ks < 2; ++ks) {
#pragma unroll
            for (int g = 0; g < 8; ++g) {
                int sidx = ((g * 16 + ln) * 64 + ks * 32 + kq) ^ ((ln & 7) << 3);
                bf16x8 bh = *(const bf16x8*)&sBh[sidx];
                bf16x8 bl = *(const bf16x8*)&sBl[sidx];
#pragma unroll
                for (int f = 0; f < 2; ++f) {
                    acc[f][g] = __builtin_amdgcn_mfma_f32_16x16x32_bf16(ah[f * 2 + ks], bh, acc[f][g], 0, 0, 0);
                    acc[f][g] = __builtin_amdgcn_mfma_f32_16x16x32_bf16(ah[f * 2 + ks], bl, acc[f][g], 0, 0, 0);
                    acc[f][g] = __builtin_amdgcn_mfma_f32_16x16x32_bf16(al[f * 2 + ks], bh, acc[f][g], 0, 0, 0);
                }
            }
        }
    }
    // ---- epilogue: C/D layout col=lane&15, row=(lane>>4)*4+reg; rows via perm
    int rbL = m0 + wave * 32 + (lane >> 4) * 4;
#pragma unroll
    for (int f = 0; f < 2; ++f) {
#pragma unroll
        for (int r = 0; r < 4; ++r) {
            int rowL = rbL + f * 16 + r;
            if (rowL >= M) continue;
            int rowP = perm[rowL];
            float* yr = Y + (size_t)rowP * ldy + ln;
#pragma unroll
            for (int g = 0; g < 8; ++g) {
                float v = acc[f][g][r] + bv[g];
                if (relu) v = fmaxf(v, 0.f);
                yr[g * 16] = v;
            }
        }
    }
}

// ---------------- host orchestration ----------------
extern "C" void kernel_launch(void* const* d_in, const int* in_sizes, int n_in,
                              void* d_out, int out_size, void* d_ws, size_t ws_size,
                              hipStream_t stream) {
    const float* emb[4] = {(const float*)d_in[0], (const float*)d_in[1],
                           (const float*)d_in[2], (const float*)d_in[3]};
    const float* W1_l = (const float*)d_in[4];
    const float* b1 = (const float*)d_in[5];
    const float* W1_r = (const float*)d_in[6];
    const float* W2_l = (const float*)d_in[7];
    const float* b2 = (const float*)d_in[8];
    const float* W2_r = (const float*)d_in[9];
    const float* ew[8];
    for (int i = 0; i < 8; ++i) ew[i] = (const float*)d_in[10 + i];
    const int* ei_buys = (const int*)d_in[18];
    const int* ei_sea = (const int*)d_in[19];
    const int* ei_mat = (const int*)d_in[20];
    const int* ei_in = (const int*)d_in[21];

    const int NT[4] = {NUSER, NPROD, NCAT, NQRY};
    const int rowOff[4] = {0, NUSER, NUSER + NPROD, NUSER + NPROD + NCAT};
    const int nrelD[4] = {2, 3, 1, 2};
    const int wtPre[4] = {0, 49152, 114688, 147456};

    struct RelT { int s, d, slot, E; const int* src; const int* dst; const float* w; };
    // slot assignment must match wt_build relsD: user{1,3} product{0,4,7} cat{6} query{2,5}
    RelT rel[8] = {
        {0, 1, 0, EBUYS,   ei_buys,          ei_buys + EBUYS,  ew[0]},  // t0
        {1, 0, 0, EBUYS,   ei_buys + EBUYS,  ei_buys,          ew[1]},  // t1
        {0, 3, 0, ESEARCH, ei_sea,           ei_sea + ESEARCH, ew[2]},  // t2
        {3, 0, 1, ESEARCH, ei_sea + ESEARCH, ei_sea,           ew[3]},  // t3
        {3, 1, 1, EMATCH,  ei_mat,           ei_mat + EMATCH,  ew[4]},  // t4
        {1, 3, 1, EMATCH,  ei_mat + EMATCH,  ei_mat,           ew[5]},  // t5
        {1, 2, 0, EIN,     ei_in,            ei_in + EIN,      ew[6]},  // t6
        {2, 1, 2, EIN,     ei_in + EIN,      ei_in,            ew[7]},  // t7
    };

    // ---- workspace carve ----
    char* p = (char*)d_ws;
    auto carve = [&](size_t bytes) {
        char* r = p;
        p += (bytes + 255) & ~(size_t)255;
        return r;
    };
    int* offs[8];
    for (int t = 0; t < 8; ++t) offs[t] = (int*)carve(((size_t)NT[rel[t].d] + 1) * 4);
    size_t fillTot = 0;
    for (int t = 0; t < 8; ++t) fillTot += (size_t)NT[rel[t].d];
    int* fillBase = (int*)carve(fillTot * 4);
    int* fill[8];
    {
        size_t o = 0;
        for (int t = 0; t < 8; ++t) { fill[t] = fillBase + o; o += NT[rel[t].d]; }
    }
    size_t Etot = 0;
    int eoff[8];
    for (int t = 0; t < 8; ++t) { eoff[t] = (int)Etot; Etot += rel[t].E; }
    int* csr_src = (int*)carve(Etot * 4);
    float* csr_w = (float*)carve(Etot * 4);
    int* bsums = (int*)carve(64 * 4);
    unsigned short* WH = (unsigned short*)carve((size_t)2 * 196608 * 2);
    unsigned short* WL = (unsigned short*)carve((size_t)2 * 196608 * 2);
    float* bsum = (float*)carve((size_t)8 * 128 * 4);
    // degree-sort scratch + per-type permutations
    int* degbuf = (int*)carve((size_t)NUSER * 4);
    int* hist = (int*)carve(512 * 4);
    int* perm[4];
    for (int d = 0; d < 4; ++d) perm[d] = (int*)carve((size_t)NT[d] * 4);
    // layer-0 hidden state h (all 4 types stacked): 352k x 128 f32 = ~180 MB
    float* hbuf = (float*)carve((size_t)(NUSER + NPROD + NCAT + NQRY) * 128 * 4);

    // ---- CSR build (once, reused by both layers) ----
    hipMemsetAsync(fillBase, 0, fillTot * 4, stream);
    for (int t = 0; t < 8; ++t)
        count_kernel<<<(rel[t].E + 255) / 256, 256, 0, stream>>>(rel[t].dst, rel[t].E, fill[t]);
    for (int t = 0; t < 8; ++t) {
        int n = NT[rel[t].d];
        int nb = (n + 4095) / 4096;
        scan_partial<<<nb, 256, 0, stream>>>(fill[t], n, bsums);
        scan_bsums<<<1, 64, 0, stream>>>(bsums, nb);
        scan_final<<<nb, 256, 0, stream>>>(fill[t], n, bsums, offs[t]);
    }
    hipMemsetAsync(fillBase, 0, fillTot * 4, stream);
    for (int t = 0; t < 8; ++t)
        fill_kernel<<<(rel[t].E + 255) / 256, 256, 0, stream>>>(
            rel[t].src, rel[t].dst, rel[t].w, rel[t].E, offs[t], fill[t],
            csr_src + eoff[t], csr_w + eoff[t]);

    // ---- degree-equalizing permutation per dst type ----
    for (int d = 0; d < 4; ++d) {
        const int* od[3] = {nullptr, nullptr, nullptr};
        int nr = 0;
        for (int t = 0; t < 8; ++t)
            if (rel[t].d == d) od[rel[t].slot] = offs[t], ++nr;
        int n = NT[d];
        hipMemsetAsync(hist, 0, 512 * 4, stream);
        deg_kernel<<<(n + 255) / 256, 256, 0, stream>>>(
            od[0], nr > 1 ? od[1] : od[0], nr > 2 ? od[2] : od[0], nr, n, degbuf, hist);
        hist_scan<<<1, 512, 0, stream>>>(hist);
        perm_scatter<<<(n + 255) / 256, 256, 0, stream>>>(degbuf, n, hist, perm[d]);
    }

    // ---- fused split-bf16 weights (tiled + swizzled) + summed bias ----
    wt_build<<<24, 256, 0, stream>>>(W1_l, b1, W1_r, W2_l, b2, W2_r, WH, WL, bsum);

    float* dout = (float*)d_out;

    // ---- two layers; layer 0 writes hbuf, layer 1 gathers from hbuf, writes d_out ----
    for (int layer = 0; layer < 2; ++layer) {
        for (int d = 0; d < 4; ++d) {
            int n = NT[d];
            const float* self = layer == 0 ? emb[d] : hbuf + (size_t)rowOff[d] * 128;
            float* Yd = (layer == 0 ? hbuf : dout) + (size_t)rowOff[d] * 128;
            RelArg RA[3];
            int nr = 0;
            for (int t = 0; t < 8; ++t) {
                if (rel[t].d != d) continue;
                RelArg a;
                a.offs = offs[t];
                a.csr = csr_src + eoff[t];
                a.w = csr_w + eoff[t];
                a.X = layer == 0 ? emb[rel[t].s] : hbuf + (size_t)rowOff[rel[t].s] * 128;
                RA[rel[t].slot] = a;
                ++nr;
            }
            for (int s2 = nr; s2 < 3; ++s2) RA[s2] = RA[0];  // unused slots (never read)
            size_t woff = (size_t)layer * 196608 + wtPre[d];
            gemm_fused<<<(n + 127) / 128, 256, 0, stream>>>(
                self, 128, RA[0], RA[1], RA[2], perm[d],
                WH + woff, WL + woff, bsum + (size_t)(layer * 4 + d) * 128,
                Yd, 128, n, (1 + nrelD[d]) * 128,
                layer == 0 ? 1 : 0);
        }
    }
}

// Round 8
// 2772.804 us; speedup vs baseline: 1.9572x; 1.0226x over previous
//
#include <hip/hip_runtime.h>

// ---------------- problem constants ----------------
#define NUSER 200000
#define NPROD 100000
#define NCAT    2000
#define NQRY   50000
#define EBUYS  500000
#define ESEARCH 300000
#define EMATCH  300000
#define EIN     100000

// type ids: 0=user 1=product 2=category 3=query
// relations t=0..7 (weight-stack index):
//  t0 user->product, t1 product->user, t2 user->query, t3 query->user,
//  t4 query->product, t5 product->query, t6 product->category, t7 category->product
// per-dst relation slots (must match wt_build's relsD):
//  user: {t1,t3}  product: {t0,t4,t7}  category: {t6}  query: {t2,t5}

// ---------------- CSR build ----------------
__global__ __launch_bounds__(256) void count_kernel(const int* __restrict__ dst, int E,
                                                    int* __restrict__ cnt) {
    int i = blockIdx.x * 256 + threadIdx.x;
    if (i < E) atomicAdd(&cnt[dst[i]], 1);
}

__global__ __launch_bounds__(256) void scan_partial(const int* __restrict__ cnt, int n,
                                                    int* __restrict__ bsums) {
    __shared__ int sd[256];
    int base = blockIdx.x * 4096;
    int s = 0;
    for (int j = threadIdx.x; j < 4096; j += 256) {
        int idx = base + j;
        s += (idx < n) ? cnt[idx] : 0;
    }
    sd[threadIdx.x] = s;
    __syncthreads();
    for (int st = 128; st > 0; st >>= 1) {
        if (threadIdx.x < st) sd[threadIdx.x] += sd[threadIdx.x + st];
        __syncthreads();
    }
    if (threadIdx.x == 0) bsums[blockIdx.x] = sd[0];
}

__global__ __launch_bounds__(64) void scan_bsums(int* __restrict__ bs, int nb) {
    int lane = threadIdx.x;
    int orig = (lane < nb) ? bs[lane] : 0;
    int v = orig;
    for (int off = 1; off < 64; off <<= 1) {
        int t = __shfl_up(v, off);
        if (lane >= off) v += t;
    }
    if (lane < nb) bs[lane] = v - orig;  // exclusive
}

__global__ __launch_bounds__(256) void scan_final(const int* __restrict__ cnt, int n,
                                                  const int* __restrict__ bsums,
                                                  int* __restrict__ offs) {
    __shared__ int tsum[256];
    int base = blockIdx.x * 4096;
    int tid = threadIdx.x;
    int local[16];
    int s = 0;
#pragma unroll
    for (int j = 0; j < 16; ++j) {
        int idx = base + tid * 16 + j;
        int v = (idx < n) ? cnt[idx] : 0;
        s += v;
        local[j] = s;
    }
    tsum[tid] = s;
    __syncthreads();
    int v = s;
    for (int off = 1; off < 256; off <<= 1) {
        int t = (tid >= off) ? tsum[tid - off] : 0;
        __syncthreads();
        v += t;
        tsum[tid] = v;
        __syncthreads();
    }
    int tpre = v - s;
    int bpre = bsums[blockIdx.x];
#pragma unroll
    for (int j = 0; j < 16; ++j) {
        int idx = base + tid * 16 + j;
        if (idx < n) offs[idx + 1] = bpre + tpre + local[j];
    }
    if (blockIdx.x == 0 && tid == 0) offs[0] = 0;
}

__global__ __launch_bounds__(256) void fill_kernel(const int* __restrict__ src,
                                                   const int* __restrict__ dst,
                                                   const float* __restrict__ w, int E,
                                                   const int* __restrict__ offs,
                                                   int* __restrict__ fill,
                                                   int* __restrict__ csr_src,
                                                   float* __restrict__ csr_w) {
    int i = blockIdx.x * 256 + threadIdx.x;
    if (i >= E) return;
    int d = dst[i];
    int slot = offs[d] + atomicAdd(&fill[d], 1);
    csr_src[slot] = src[i];
    csr_w[slot] = w[i];
}

// ---------------- f32 -> bf16 hi/lo split helpers ----------------
// hi = truncated top 16 bits (exact bf16); lo = bf16(trunc) of residual.
// a ~= hi + lo with relative error ~2^-16; dropped lo*lo term in the GEMM is
// ~2^-16 relative => result is f32-equivalent for this problem's magnitudes.
__device__ __forceinline__ unsigned pk_hi(float a, float b) {
    return (__float_as_uint(b) & 0xffff0000u) | (__float_as_uint(a) >> 16);
}
__device__ __forceinline__ float f32_trunc(float a) {
    return __uint_as_float(__float_as_uint(a) & 0xffff0000u);
}

typedef short bf16x8 __attribute__((ext_vector_type(8)));
typedef float f32x4 __attribute__((ext_vector_type(4)));

__device__ __forceinline__ bf16x8 pack_hi8(const float4& a, const float4& b) {
    union { unsigned u[4]; bf16x8 v; } r;
    r.u[0] = pk_hi(a.x, a.y);
    r.u[1] = pk_hi(a.z, a.w);
    r.u[2] = pk_hi(b.x, b.y);
    r.u[3] = pk_hi(b.z, b.w);
    return r.v;
}
__device__ __forceinline__ bf16x8 pack_lo8(const float4& a, const float4& b) {
    union { unsigned u[4]; bf16x8 v; } r;
    r.u[0] = pk_hi(a.x - f32_trunc(a.x), a.y - f32_trunc(a.y));
    r.u[1] = pk_hi(a.z - f32_trunc(a.z), a.w - f32_trunc(a.w));
    r.u[2] = pk_hi(b.x - f32_trunc(b.x), b.y - f32_trunc(b.y));
    r.u[3] = pk_hi(b.z - f32_trunc(b.z), b.w - f32_trunc(b.w));
    return r.v;
}

// ---------------- fused weight build ----------------
// Produces bf16 hi/lo planes of the concat-K B matrix, stored as a sequence of
// 64-k tiles per (layer,dst): tile t is 128n x 64k = 8192 shorts, PRE-SWIZZLED:
//   elem (n, kk) lives at tile*8192 + ((n*64 + kk) ^ ((n&7)<<3))
// so the GEMM can copy it LINEARLY into LDS and read conflict-free ds_read_b128
// with the same XOR (Guideline 21: source perm == read perm).
__global__ __launch_bounds__(256) void wt_build(const float* __restrict__ W1_l,
                                                const float* __restrict__ b1,
                                                const float* __restrict__ W1_r,
                                                const float* __restrict__ W2_l,
                                                const float* __restrict__ b2,
                                                const float* __restrict__ W2_r,
                                                unsigned short* __restrict__ WH,
                                                unsigned short* __restrict__ WL,
                                                float* __restrict__ bsum) {
    const int relsD[4][3] = {{1, 3, -1}, {0, 4, 7}, {6, -1, -1}, {2, 5, -1}};
    const int nrelD[4] = {2, 3, 1, 2};
    const int pre[4] = {0, 49152, 114688, 147456};  // elements, per-layer prefix
    int bid = blockIdx.x;
    int l = bid / 12, r = bid % 12;
    int d, s;
    if (r < 3) { d = 0; s = r; }
    else if (r < 7) { d = 1; s = r - 3; }
    else if (r < 9) { d = 2; s = r - 7; }
    else { d = 3; s = r - 9; }
    const float* Wl = l ? W2_l : W1_l;
    const float* Wr = l ? W2_r : W1_r;
    const float* bb = l ? b2 : b1;
    size_t base = (size_t)l * 196608 + pre[d];
    if (s == 0 && threadIdx.x < 128) {
        float acc = 0.f;
        for (int j = 0; j < nrelD[d]; ++j) acc += bb[relsD[d][j] * 128 + threadIdx.x];
        bsum[(l * 4 + d) * 128 + threadIdx.x] = acc;
    }
    for (int p = 0; p < 8; ++p) {
        int c = threadIdx.x + p * 256;
        int n = c >> 4, ic = (c & 15) * 8;
        float e[8];
        if (s == 0) {
#pragma unroll
            for (int q = 0; q < 8; ++q) e[q] = 0.f;
            for (int j = 0; j < nrelD[d]; ++j) {
                const float* wsrc = Wl + relsD[d][j] * 16384 + n * 128 + ic;
#pragma unroll
                for (int q = 0; q < 8; ++q) e[q] += wsrc[q];
            }
        } else {
            const float* wsrc = Wr + relsD[d][s - 1] * 16384 + n * 128 + ic;
#pragma unroll
            for (int q = 0; q < 8; ++q) e[q] = wsrc[q];
        }
        uint4 hi, lo;
        hi.x = pk_hi(e[0], e[1]); hi.y = pk_hi(e[2], e[3]);
        hi.z = pk_hi(e[4], e[5]); hi.w = pk_hi(e[6], e[7]);
        float lv[8];
#pragma unroll
        for (int q = 0; q < 8; ++q) lv[q] = e[q] - f32_trunc(e[q]);
        lo.x = pk_hi(lv[0], lv[1]); lo.y = pk_hi(lv[2], lv[3]);
        lo.z = pk_hi(lv[4], lv[5]); lo.w = pk_hi(lv[6], lv[7]);
        int tile = s * 2 + (ic >> 6);
        int kk = ic & 63;
        size_t go = base + (size_t)tile * 8192 + (size_t)(((n * 64 + kk) ^ ((n & 7) << 3)));
        *(uint4*)(WH + go) = hi;
        *(uint4*)(WL + go) = lo;
    }
}

// ---------------- per-relation / per-type args for the merged fused GEMM ----------
struct RelArg {
    const int* offs;    // [n_dst+1]
    const int* csr;     // src indices, CSR order
    const float* w;     // edge weights, CSR order
    const float* X;     // source-type feature rows [n_src][128]
};

struct TypeArg {
    const float* self;              // [M][128]
    float* Y;                       // [M][128]
    const unsigned short* WH;       // per-(layer,type) swizzled tiles
    const unsigned short* WL;
    const float* bias;              // [128]
    RelArg R[3];
    int M, K, blk0, relu;           // blk0 = first block id of this type
};

// ---------------- merged fused gather + concat-K MFMA GEMM ----------------
// One launch covers all 4 dst types of a layer (block -> type via blk0 ranges):
// amortizes ramp/tail across types; long-walk category blocks go first.
// Split-bf16 (hi/lo) f32 emulation: C = Ah*Bh + Ah*Bl + Al*Bh (f32 accum).
// A self tiles: streamed global->reg (consecutive rows, coalesced).
// A agg tiles: fused CSR gather-mean, f=0/f=1 walks INTERLEAVED (2x MLP,
// max(d0,d1) trips). Same per-row ascending accumulation order as all prior
// rounds => bitwise-identical output.
// B: staged to LDS per k-tile (pure copy of pre-swizzled tiles), immediately
// (load->write->barrier) so a slow-gather wave only delays its own MFMAs.
__global__ __launch_bounds__(256, 4) void gemm_fused(TypeArg A0, TypeArg A1,
                                                     TypeArg A2, TypeArg A3) {
    __shared__ unsigned short sBh[8192];  // one 64-k B tile, hi plane, swizzled
    __shared__ unsigned short sBl[8192];  // lo plane
    int bid = blockIdx.x;
    const TypeArg* T;
    if (bid >= A3.blk0) T = &A3;
    else if (bid >= A2.blk0) T = &A2;
    else if (bid >= A1.blk0) T = &A1;
    else T = &A0;
    int M = T->M, K = T->K, relu = T->relu;
    const unsigned short* WH = T->WH;
    const unsigned short* WL = T->WL;
    float* Y = T->Y;

    int tid = threadIdx.x;
    int lane = tid & 63;
    int wave = tid >> 6;  // 0..3
    int m0 = (bid - T->blk0) * 128;
    int ln = lane & 15;
    int kq = (lane >> 4) * 8;   // lane's k-offset within a 32-k step
    int rowA = wave * 32 + ln;  // tile-row for f=0; f=1 adds 16

    int pr0 = m0 + rowA;        // f=0 row
    int pr1 = pr0 + 16;         // f=1 row
    if (pr0 >= M) pr0 = -1;
    if (pr1 >= M) pr1 = -1;

    f32x4 acc[2][8] = {};  // [m-frag][n-frag]

    float bv[8];
#pragma unroll
    for (int g = 0; g < 8; ++g) bv[g] = T->bias[g * 16 + ln];

    int nt = K >> 6;
    for (int t = 0; t < nt; ++t) {
        const unsigned short* wht = WH + (size_t)t * 8192;
        const unsigned short* wlt = WL + (size_t)t * 8192;
        __syncthreads();  // all waves done reading previous tile's LDS
        // ---- stage B tile: global -> reg -> LDS (linear copy of swizzled tile)
        uint4 rh[4], rl[4];
#pragma unroll
        for (int p = 0; p < 4; ++p) {
            rh[p] = *(const uint4*)(wht + (size_t)(tid + p * 256) * 8);
            rl[p] = *(const uint4*)(wlt + (size_t)(tid + p * 256) * 8);
        }
#pragma unroll
        for (int p = 0; p < 4; ++p) {
            *(uint4*)&sBh[(size_t)(tid + p * 256) * 8] = rh[p];
            *(uint4*)&sBl[(size_t)(tid + p * 256) * 8] = rl[p];
        }
        __syncthreads();  // B tile staged; gathers below overlap other waves' MFMAs
        // ---- produce A fragments: Af[(f*2+ks)*2+half] covers cols kq+ks*32+half*4..+4
        float4 Af[8];
        if (t < 2) {
            // self tile: stream consecutive rows (coalesced)
            int kc0 = t * 64;
#pragma unroll
            for (int f = 0; f < 2; ++f) {
                int prf = f ? pr1 : pr0;
#pragma unroll
                for (int ks = 0; ks < 2; ++ks) {
                    float4 v0 = {0.f, 0.f, 0.f, 0.f}, v1 = {0.f, 0.f, 0.f, 0.f};
                    if (prf >= 0) {
                        const float* pr_ = T->self + (size_t)prf * 128 + kc0 + kq;
                        v0 = *(const float4*)(pr_ + ks * 32);
                        v1 = *(const float4*)(pr_ + ks * 32 + 4);
                    }
                    Af[(f * 2 + ks) * 2 + 0] = v0;
                    Af[(f * 2 + ks) * 2 + 1] = v1;
                }
            }
        } else {
            // agg tile: fused CSR gather-mean, f=0/f=1 interleaved (2x MLP)
            int r = (t - 2) >> 1;
            int kc0r = ((t - 2) & 1) * 64;
            const RelArg* R = &T->R[r];
            float4 z = {0.f, 0.f, 0.f, 0.f};
#pragma unroll
            for (int j = 0; j < 8; ++j) Af[j] = z;
            int b0 = 0, e0 = 0, b1 = 0, e1 = 0;
            if (pr0 >= 0) { b0 = R->offs[pr0]; e0 = R->offs[pr0 + 1]; }
            if (pr1 >= 0) { b1 = R->offs[pr1]; e1 = R->offs[pr1 + 1]; }
            int i0 = b0, i1 = b1;
            int s0 = 0, s1 = 0;
            float w0v = 0.f, w1v = 0.f;
            if (i0 < e0) { s0 = R->csr[i0]; w0v = R->w[i0]; }
            if (i1 < e1) { s1 = R->csr[i1]; w1v = R->w[i1]; }
            while (i0 < e0 || i1 < e1) {
                bool a0 = i0 < e0, a1 = i1 < e1;
                float4 u0, u1, u2, u3, q0, q1, q2, q3;
                if (a0) {
                    const float* xp = R->X + (size_t)s0 * 128 + kc0r + kq;
                    u0 = *(const float4*)(xp + 0);
                    u1 = *(const float4*)(xp + 4);
                    u2 = *(const float4*)(xp + 32);
                    u3 = *(const float4*)(xp + 36);
                }
                if (a1) {
                    const float* xp = R->X + (size_t)s1 * 128 + kc0r + kq;
                    q0 = *(const float4*)(xp + 0);
                    q1 = *(const float4*)(xp + 4);
                    q2 = *(const float4*)(xp + 32);
                    q3 = *(const float4*)(xp + 36);
                }
                if (a0) ++i0;
                if (a1) ++i1;
                int sn0 = s0, sn1 = s1;
                float wn0 = w0v, wn1 = w1v;
                if (i0 < e0) { sn0 = R->csr[i0]; wn0 = R->w[i0]; }  // prefetch under gather
                if (i1 < e1) { sn1 = R->csr[i1]; wn1 = R->w[i1]; }
                if (a0) {
                    Af[0].x += w0v * u0.x; Af[0].y += w0v * u0.y; Af[0].z += w0v * u0.z; Af[0].w += w0v * u0.w;
                    Af[1].x += w0v * u1.x; Af[1].y += w0v * u1.y; Af[1].z += w0v * u1.z; Af[1].w += w0v * u1.w;
                    Af[2].x += w0v * u2.x; Af[2].y += w0v * u2.y; Af[2].z += w0v * u2.z; Af[2].w += w0v * u2.w;
                    Af[3].x += w0v * u3.x; Af[3].y += w0v * u3.y; Af[3].z += w0v * u3.z; Af[3].w += w0v * u3.w;
                }
                if (a1) {
                    Af[4].x += w1v * q0.x; Af[4].y += w1v * q0.y; Af[4].z += w1v * q0.z; Af[4].w += w1v * q0.w;
                    Af[5].x += w1v * q1.x; Af[5].y += w1v * q1.y; Af[5].z += w1v * q1.z; Af[5].w += w1v * q1.w;
                    Af[6].x += w1v * q2.x; Af[6].y += w1v * q2.y; Af[6].z += w1v * q2.z; Af[6].w += w1v * q2.w;
                    Af[7].x += w1v * q3.x; Af[7].y += w1v * q3.y; Af[7].z += w1v * q3.z; Af[7].w += w1v * q3.w;
                }
                s0 = sn0; w0v = wn0; s1 = sn1; w1v = wn1;
            }
            if (e0 > b0) {
                float inv = 1.f / (float)(e0 - b0);
#pragma unroll
                for (int j = 0; j < 4; ++j) {
                    Af[j].x *= inv; Af[j].y *= inv; Af[j].z *= inv; Af[j].w *= inv;
                }
            }
            if (e1 > b1) {
                float inv = 1.f / (float)(e1 - b1);
#pragma unroll
                for (int j = 4; j < 8; ++j) {
                    Af[j].x *= inv; Af[j].y *= inv; Af[j].z *= inv; Af[j].w *= inv;
                }
            }
        }
        // ---- pack A to bf16 hi/lo in-reg
        bf16x8 ah[4], al[4];
#pragma unroll
        for (int j = 0; j < 4; ++j) {
            ah[j] = pack_hi8(Af[j * 2], Af[j * 2 + 1]);
            al[j] = pack_lo8(Af[j * 2], Af[j * 2 + 1]);
        }
        // ---- compute: 2 k-steps of 32; B frags from LDS (swizzled, conflict-free)
#pragma unroll
        for (int ks = 0; ks < 2; ++ks) {
#pragma unroll
            for (int g = 0; g < 8; ++g) {
                int sidx = ((g * 16 + ln) * 64 + ks * 32 + kq) ^ ((ln & 7) << 3);
                bf16x8 bh = *(const bf16x8*)&sBh[sidx];
                bf16x8 bl = *(const bf16x8*)&sBl[sidx];
#pragma unroll
                for (int f = 0; f < 2; ++f) {
                    acc[f][g] = __builtin_amdgcn_mfma_f32_16x16x32_bf16(ah[f * 2 + ks], bh, acc[f][g], 0, 0, 0);
                    acc[f][g] = __builtin_amdgcn_mfma_f32_16x16x32_bf16(ah[f * 2 + ks], bl, acc[f][g], 0, 0, 0);
                    acc[f][g] = __builtin_amdgcn_mfma_f32_16x16x32_bf16(al[f * 2 + ks], bh, acc[f][g], 0, 0, 0);
                }
            }
        }
    }
    // ---- epilogue: C/D layout col=lane&15, row=(lane>>4)*4+reg (m89-verified)
    int rbase = m0 + wave * 32 + (lane >> 4) * 4;
#pragma unroll
    for (int f = 0; f < 2; ++f) {
#pragma unroll
        for (int r = 0; r < 4; ++r) {
            int row = rbase + f * 16 + r;
            if (row >= M) continue;
            float* yr = Y + (size_t)row * 128 + ln;
#pragma unroll
            for (int g = 0; g < 8; ++g) {
                float v = acc[f][g][r] + bv[g];
                if (relu) v = fmaxf(v, 0.f);
                yr[g * 16] = v;
            }
        }
    }
}

// ---------------- host orchestration ----------------
extern "C" void kernel_launch(void* const* d_in, const int* in_sizes, int n_in,
                              void* d_out, int out_size, void* d_ws, size_t ws_size,
                              hipStream_t stream) {
    const float* emb[4] = {(const float*)d_in[0], (const float*)d_in[1],
                           (const float*)d_in[2], (const float*)d_in[3]};
    const float* W1_l = (const float*)d_in[4];
    const float* b1 = (const float*)d_in[5];
    const float* W1_r = (const float*)d_in[6];
    const float* W2_l = (const float*)d_in[7];
    const float* b2 = (const float*)d_in[8];
    const float* W2_r = (const float*)d_in[9];
    const float* ew[8];
    for (int i = 0; i < 8; ++i) ew[i] = (const float*)d_in[10 + i];
    const int* ei_buys = (const int*)d_in[18];
    const int* ei_sea = (const int*)d_in[19];
    const int* ei_mat = (const int*)d_in[20];
    const int* ei_in = (const int*)d_in[21];

    const int NT[4] = {NUSER, NPROD, NCAT, NQRY};
    const int rowOff[4] = {0, NUSER, NUSER + NPROD, NUSER + NPROD + NCAT};
    const int nrelD[4] = {2, 3, 1, 2};
    const int wtPre[4] = {0, 49152, 114688, 147456};

    struct RelT { int s, d, slot, E; const int* src; const int* dst; const float* w; };
    // slot assignment must match wt_build relsD: user{1,3} product{0,4,7} cat{6} query{2,5}
    RelT rel[8] = {
        {0, 1, 0, EBUYS,   ei_buys,          ei_buys + EBUYS,  ew[0]},  // t0
        {1, 0, 0, EBUYS,   ei_buys + EBUYS,  ei_buys,          ew[1]},  // t1
        {0, 3, 0, ESEARCH, ei_sea,           ei_sea + ESEARCH, ew[2]},  // t2
        {3, 0, 1, ESEARCH, ei_sea + ESEARCH, ei_sea,           ew[3]},  // t3
        {3, 1, 1, EMATCH,  ei_mat,           ei_mat + EMATCH,  ew[4]},  // t4
        {1, 3, 1, EMATCH,  ei_mat + EMATCH,  ei_mat,           ew[5]},  // t5
        {1, 2, 0, EIN,     ei_in,            ei_in + EIN,      ew[6]},  // t6
        {2, 1, 2, EIN,     ei_in + EIN,      ei_in,            ew[7]},  // t7
    };

    // ---- workspace carve ----
    char* p = (char*)d_ws;
    auto carve = [&](size_t bytes) {
        char* r = p;
        p += (bytes + 255) & ~(size_t)255;
        return r;
    };
    int* offs[8];
    for (int t = 0; t < 8; ++t) offs[t] = (int*)carve(((size_t)NT[rel[t].d] + 1) * 4);
    size_t fillTot = 0;
    for (int t = 0; t < 8; ++t) fillTot += (size_t)NT[rel[t].d];
    int* fillBase = (int*)carve(fillTot * 4);
    int* fill[8];
    {
        size_t o = 0;
        for (int t = 0; t < 8; ++t) { fill[t] = fillBase + o; o += NT[rel[t].d]; }
    }
    size_t Etot = 0;
    int eoff[8];
    for (int t = 0; t < 8; ++t) { eoff[t] = (int)Etot; Etot += rel[t].E; }
    int* csr_src = (int*)carve(Etot * 4);
    float* csr_w = (float*)carve(Etot * 4);
    int* bsums = (int*)carve(64 * 4);
    unsigned short* WH = (unsigned short*)carve((size_t)2 * 196608 * 2);
    unsigned short* WL = (unsigned short*)carve((size_t)2 * 196608 * 2);
    float* bsum = (float*)carve((size_t)8 * 128 * 4);
    // layer-0 hidden state h (all 4 types stacked): 352k x 128 f32 = ~180 MB
    float* hbuf = (float*)carve((size_t)(NUSER + NPROD + NCAT + NQRY) * 128 * 4);

    // ---- CSR build (once, reused by both layers) ----
    hipMemsetAsync(fillBase, 0, fillTot * 4, stream);
    for (int t = 0; t < 8; ++t)
        count_kernel<<<(rel[t].E + 255) / 256, 256, 0, stream>>>(rel[t].dst, rel[t].E, fill[t]);
    for (int t = 0; t < 8; ++t) {
        int n = NT[rel[t].d];
        int nb = (n + 4095) / 4096;
        scan_partial<<<nb, 256, 0, stream>>>(fill[t], n, bsums);
        scan_bsums<<<1, 64, 0, stream>>>(bsums, nb);
        scan_final<<<nb, 256, 0, stream>>>(fill[t], n, bsums, offs[t]);
    }
    hipMemsetAsync(fillBase, 0, fillTot * 4, stream);
    for (int t = 0; t < 8; ++t)
        fill_kernel<<<(rel[t].E + 255) / 256, 256, 0, stream>>>(
            rel[t].src, rel[t].dst, rel[t].w, rel[t].E, offs[t], fill[t],
            csr_src + eoff[t], csr_w + eoff[t]);

    // ---- fused split-bf16 weights (tiled + swizzled) + summed bias ----
    wt_build<<<24, 256, 0, stream>>>(W1_l, b1, W1_r, W2_l, b2, W2_r, WH, WL, bsum);

    float* dout = (float*)d_out;

    // ---- two layers, ONE launch each; block->type order: cat, query, product, user
    // (long-walk category blocks first; cheap user blocks form the tail)
    const int order[4] = {2, 3, 1, 0};
    for (int layer = 0; layer < 2; ++layer) {
        TypeArg TA[4];
        int blk = 0;
        for (int oi = 0; oi < 4; ++oi) {
            int d = order[oi];
            int n = NT[d];
            TypeArg a;
            a.self = layer == 0 ? emb[d] : hbuf + (size_t)rowOff[d] * 128;
            a.Y = (layer == 0 ? hbuf : dout) + (size_t)rowOff[d] * 128;
            size_t woff = (size_t)layer * 196608 + wtPre[d];
            a.WH = WH + woff;
            a.WL = WL + woff;
            a.bias = bsum + (size_t)(layer * 4 + d) * 128;
            a.M = n;
            a.K = (1 + nrelD[d]) * 128;
            a.blk0 = blk;
            a.relu = layer == 0 ? 1 : 0;
            int nr = 0;
            for (int t = 0; t < 8; ++t) {
                if (rel[t].d != d) continue;
                RelArg ra;
                ra.offs = offs[t];
                ra.csr = csr_src + eoff[t];
                ra.w = csr_w + eoff[t];
                ra.X = layer == 0 ? emb[rel[t].s] : hbuf + (size_t)rowOff[rel[t].s] * 128;
                a.R[rel[t].slot] = ra;
                ++nr;
            }
            for (int s2 = nr; s2 < 3; ++s2) a.R[s2] = a.R[0];  // unused (never read)
            TA[oi] = a;
            blk += (n + 127) / 128;
        }
        gemm_fused<<<blk, 256, 0, stream>>>(TA[0], TA[1], TA[2], TA[3]);
    }
}